// Round 2
// baseline (2288.410 us; speedup 1.0000x reference)
//
#include <hip/hip_runtime.h>
#include <hip/hip_bf16.h>

typedef __hip_bfloat16 bf16;

#define NB   128   // graphs
#define NPGX 40    // nodes per graph
#define NNODE 5120 // total nodes
#define NE   20000 // edges
#define LPX  512   // protein seq len
#define MAXNX 45

__device__ __forceinline__ float tofl(bf16 v) { return __bfloat162float(v); }
__device__ __forceinline__ float tofl(float v) { return v; }
__device__ __forceinline__ void stv(float* p, float v) { *p = v; }
__device__ __forceinline__ void stv(bf16* p, float v) { *p = __float2bfloat16(v); }

// ---------------- generic tiled GEMM: C = act(A[M,K] @ B[K,N] + bias) ----------------
// A: bf16 or fp32 row-major (optional protein-gather on rows), B: fp32 row-major,
// C: fp32 or bf16. M,N multiples of 64; K arbitrary (guarded).
template <typename TA, typename TO, int ACT, bool GATHER>
__global__ __launch_bounds__(256) void gemm_k(
    const TA* __restrict__ A, const float* __restrict__ B, const float* __restrict__ bias,
    TO* __restrict__ C, int M, int N, int K, const int* __restrict__ tgt)
{
    __shared__ float sA[16][65];
    __shared__ float sB[16][65];
    const int m0 = blockIdx.x * 64;
    const int n0 = blockIdx.y * 64;
    const int t = threadIdx.x;
    const int tx = t & 15, ty = t >> 4;
    float acc[4][4] = {};
    for (int k0 = 0; k0 < K; k0 += 16) {
#pragma unroll
        for (int i = 0; i < 4; i++) {           // A tile 64x16
            int idx = t + i * 256;
            int mm = idx >> 4, kk = idx & 15;
            int k = k0 + kk;
            float v = 0.f;
            if (k < K) {
                long row = m0 + mm;
                if (GATHER) { int bb = (int)(row >> 9); int l = (int)(row & 511); row = (long)tgt[bb] * LPX + l; }
                v = tofl(A[row * (long)K + k]);
            }
            sA[kk][mm] = v;
        }
#pragma unroll
        for (int i = 0; i < 4; i++) {           // B tile 16x64
            int idx = t + i * 256;
            int kk = idx >> 6, nn = idx & 63;
            int k = k0 + kk;
            float v = 0.f;
            if (k < K) v = B[(long)k * N + n0 + nn];
            sB[kk][nn] = v;
        }
        __syncthreads();
#pragma unroll
        for (int kk = 0; kk < 16; kk++) {
            float a[4], b[4];
#pragma unroll
            for (int i = 0; i < 4; i++) a[i] = sA[kk][ty * 4 + i];
#pragma unroll
            for (int j = 0; j < 4; j++) b[j] = sB[kk][tx * 4 + j];
#pragma unroll
            for (int i = 0; i < 4; i++)
#pragma unroll
                for (int j = 0; j < 4; j++) acc[i][j] = fmaf(a[i], b[j], acc[i][j]);
        }
        __syncthreads();
    }
#pragma unroll
    for (int i = 0; i < 4; i++) {
        int m = m0 + ty * 4 + i;
#pragma unroll
        for (int j = 0; j < 4; j++) {
            int n = n0 + tx * 4 + j;
            float v = acc[i][j];
            if (bias) v += bias[n];
            if (ACT == 1) v = fmaxf(v, 0.f);
            else if (ACT == 2) v = tanhf(v);
            stv(&C[(long)m * N + n], v);
        }
    }
}

// ---------------- GCN graph preprocessing ----------------
__global__ void k_count(const int* __restrict__ dst, int* __restrict__ cnt, int E) {
    int e = blockIdx.x * 256 + threadIdx.x;
    if (e < E) atomicAdd(&cnt[dst[e]], 1);
}

__global__ void k_scan(const int* __restrict__ cnt, int* __restrict__ row_start,
                       float* __restrict__ dinv, float* __restrict__ deginv, int n) {
    __shared__ int sd[1024];
    __shared__ int scarry;
    int t = threadIdx.x;
    if (t == 0) scarry = 0;
    __syncthreads();
    for (int base = 0; base < n; base += 1024) {
        int i = base + t;
        int v = (i < n) ? cnt[i] : 0;
        sd[t] = v;
        __syncthreads();
        for (int off = 1; off < 1024; off <<= 1) {
            int tmp = (t >= off) ? sd[t - off] : 0;
            __syncthreads();
            sd[t] += tmp;
            __syncthreads();
        }
        int carry = scarry;
        if (i < n) {
            row_start[i] = carry + sd[t] - v;
            float deg = (float)(v + 1);
            dinv[i] = rsqrtf(deg);
            deginv[i] = 1.f / deg;
        }
        __syncthreads();
        if (t == 1023) scarry = carry + sd[1023];
        __syncthreads();
    }
    if (t == 0) row_start[n] = scarry;
}

__global__ void k_fill(const int* __restrict__ src, const int* __restrict__ dst,
                       const int* __restrict__ row_start, int* __restrict__ cursor,
                       int* __restrict__ col, float* __restrict__ val,
                       const float* __restrict__ dinv, int E) {
    int e = blockIdx.x * 256 + threadIdx.x;
    if (e >= E) return;
    int d = dst[e], s = src[e];
    int p = atomicAdd(&cursor[d], 1);
    int idx = row_start[d] + p;
    col[idx] = s;
    val[idx] = dinv[s] * dinv[d];
}

// out[i,f] = relu( xw[i,f]/deg[i] + sum_e val*xw[col,f] + b[f] )
// DENSE: write to to_dense_batch position (g*45+pos) instead of node index.
template <bool DENSE>
__global__ void k_agg(const float* __restrict__ xw, const float* __restrict__ deginv,
                      const int* __restrict__ row_start, const int* __restrict__ col,
                      const float* __restrict__ val, const float* __restrict__ bias,
                      float* __restrict__ out, int F) {
    int idx = blockIdx.x * 256 + threadIdx.x;
    if (idx >= NNODE * F) return;
    int i = idx / F, f = idx - i * F;
    float s = xw[idx] * deginv[i];
    int e0 = row_start[i], e1 = row_start[i + 1];
    for (int e = e0; e < e1; e++) s += val[e] * xw[col[e] * F + f];
    s += bias[f];
    s = fmaxf(s, 0.f);
    if (DENSE) {
        int g = i / NPGX, pos = i - g * NPGX;
        out[(g * MAXNX + pos) * F + f] = s;
    } else {
        out[idx] = s;
    }
}

// ---------------- co-attention ----------------
// C[b,l,s] = tanh( sum_m tWb[b*512+l,m] * hd2[b*45+s,m] )
__global__ __launch_bounds__(256) void k_C(const bf16* __restrict__ tWb,
                                           const float* __restrict__ hd2, float* __restrict__ Cb) {
    int b = blockIdx.x, lt = blockIdx.y;
    __shared__ float sx[45][129];
    for (int t = threadIdx.x; t < 45 * 128; t += 256)
        sx[t >> 7][t & 127] = hd2[(b * 45 + (t >> 7)) * 128 + (t & 127)];
    __syncthreads();
    for (int t = threadIdx.x; t < 64 * 45; t += 256) {
        int ll = t / 45, s = t - ll * 45;
        int l = lt * 64 + ll;
        const bf16* arow = tWb + ((long)b * 512 + l) * 128;
        float a = 0.f;
        for (int m = 0; m < 128; m++) a += tofl(arow[m]) * sx[s][m];
        Cb[((long)b * 512 + l) * 45 + s] = tanhf(a);
    }
}

// Wcx[b,k,s] = sum_m Wc[k,m] * hd2[b*45+s,m]
__global__ __launch_bounds__(256) void k_wcx(const float* __restrict__ Wc,
                                             const float* __restrict__ hd2, float* __restrict__ Wcx) {
    int b = blockIdx.x;
    __shared__ float sW[32][129];
    __shared__ float sx[45][129];
    for (int t = threadIdx.x; t < 32 * 128; t += 256) sW[t >> 7][t & 127] = Wc[t];
    for (int t = threadIdx.x; t < 45 * 128; t += 256)
        sx[t >> 7][t & 127] = hd2[(b * 45 + (t >> 7)) * 128 + (t & 127)];
    __syncthreads();
    for (int t = threadIdx.x; t < 32 * 45; t += 256) {
        int k = t / 45, s = t - k * 45;
        float a = 0.f;
        for (int m = 0; m < 128; m++) a += sW[k][m] * sx[s][m];
        Wcx[(b * 32 + k) * 45 + s] = a;
    }
}

// Wpt[b,k,l] = sum_m Wp[k,m] * t2[b*512+l,m]
__global__ __launch_bounds__(256) void k_wpt(const float* __restrict__ Wp,
                                             const bf16* __restrict__ t2, float* __restrict__ Wpt) {
    int b = blockIdx.x, lt = blockIdx.y;
    __shared__ float sW[32][129];
    __shared__ float sT[64][129];
    for (int t = threadIdx.x; t < 32 * 128; t += 256) sW[t >> 7][t & 127] = Wp[t];
    for (int t = threadIdx.x; t < 64 * 128; t += 256) {
        int l = t >> 7, m = t & 127;
        sT[l][m] = tofl(t2[((long)b * 512 + lt * 64 + l) * 128 + m]);
    }
    __syncthreads();
    for (int t = threadIdx.x; t < 32 * 64; t += 256) {
        int k = t >> 6, l = t & 63;
        float a = 0.f;
        for (int m = 0; m < 128; m++) a += sW[k][m] * sT[l][m];
        Wpt[((long)(b * 32 + k)) * 512 + lt * 64 + l] = a;
    }
}

// Hc[b,k,s] = tanh( Wcx[b,k,s] + sum_l Wpt[b,k,l]*C[b,l,s] )
__global__ __launch_bounds__(256) void k_hc(const float* __restrict__ Wpt,
                                            const float* __restrict__ Cb,
                                            const float* __restrict__ Wcx, float* __restrict__ Hc) {
    int b = blockIdx.x;
    __shared__ float sW[32][130];
    __shared__ float sC[128][46];
    float acc[6] = {0.f, 0.f, 0.f, 0.f, 0.f, 0.f};
    for (int lc = 0; lc < 4; lc++) {
        for (int t = threadIdx.x; t < 32 * 128; t += 256) {
            int k = t >> 7, l = t & 127;
            sW[k][l] = Wpt[((long)(b * 32 + k)) * 512 + lc * 128 + l];
        }
        for (int t = threadIdx.x; t < 128 * 45; t += 256) {
            int l = t / 45, s = t - l * 45;
            sC[l][s] = Cb[((long)b * 512 + lc * 128 + l) * 45 + s];
        }
        __syncthreads();
#pragma unroll
        for (int u = 0; u < 6; u++) {
            int o = threadIdx.x + u * 256;
            if (o < 32 * 45) {
                int k = o / 45, s = o - k * 45;
                float a = acc[u];
                for (int l = 0; l < 128; l++) a += sW[k][l] * sC[l][s];
                acc[u] = a;
            }
        }
        __syncthreads();
    }
    for (int u = 0; u < 6; u++) {
        int o = threadIdx.x + u * 256;
        if (o < 32 * 45) {
            int k = o / 45, s = o - k * 45;
            int idx = (b * 32 + k) * 45 + s;
            Hc[idx] = tanhf(Wcx[idx] + acc[u]);
        }
    }
}

// Hp[b,k,l] = tanh( Wpt[b,k,l] + sum_s Wcx[b,k,s]*C[b,l,s] )  (in-place into Wpt)
__global__ __launch_bounds__(256) void k_hp(const float* __restrict__ Wcx,
                                            const float* __restrict__ Cb, float* __restrict__ Wpt) {
    int b = blockIdx.x;
    __shared__ float sW[32][46];
    for (int t = threadIdx.x; t < 32 * 45; t += 256) {
        int k = t / 45, s = t - k * 45;
        sW[k][s] = Wcx[b * 32 * 45 + t];
    }
    __syncthreads();
    for (int t = threadIdx.x; t < 32 * 512; t += 256) {
        int l = t >> 5, k = t & 31;
        const float* crow = Cb + ((long)b * 512 + l) * 45;
        float a = 0.f;
        for (int s = 0; s < 45; s++) a += sW[k][s] * crow[s];
        long idx = ((long)(b * 32 + k)) * 512 + l;
        Wpt[idx] = tanhf(Wpt[idx] + a);
    }
}

__global__ void k_ac(const float* __restrict__ whc, const float* __restrict__ Hc,
                     float* __restrict__ ac) {
    int b = blockIdx.x, s = threadIdx.x;  // 64 threads
    float logit = -1e30f;
    if (s < 45) {
        float a = 0.f;
        for (int k = 0; k < 32; k++) a += whc[k] * Hc[(b * 32 + k) * 45 + s];
        logit = a;
    }
    float m = logit;
    for (int off = 32; off; off >>= 1) m = fmaxf(m, __shfl_xor(m, off));
    float e = (s < 45) ? expf(logit - m) : 0.f;
    float sum = e;
    for (int off = 32; off; off >>= 1) sum += __shfl_xor(sum, off);
    if (s < 45) ac[b * 45 + s] = e / sum;
}

__global__ __launch_bounds__(256) void k_ap(const float* __restrict__ whp,
                                            const float* __restrict__ Hp, float* __restrict__ ap) {
    int b = blockIdx.x, t = threadIdx.x;
    float lv[2];
#pragma unroll
    for (int u = 0; u < 2; u++) {
        int l = t + u * 256;
        float a = 0.f;
        for (int k = 0; k < 32; k++) a += whp[k] * Hp[((long)(b * 32 + k)) * 512 + l];
        lv[u] = a;
    }
    __shared__ float wred[4];
    __shared__ float wsum[4];
    float m = fmaxf(lv[0], lv[1]);
    for (int off = 32; off; off >>= 1) m = fmaxf(m, __shfl_xor(m, off));
    if ((t & 63) == 0) wred[t >> 6] = m;
    __syncthreads();
    m = fmaxf(fmaxf(wred[0], wred[1]), fmaxf(wred[2], wred[3]));
    float e0 = expf(lv[0] - m), e1 = expf(lv[1] - m);
    float s = e0 + e1;
    for (int off = 32; off; off >>= 1) s += __shfl_xor(s, off);
    if ((t & 63) == 0) wsum[t >> 6] = s;
    __syncthreads();
    s = wsum[0] + wsum[1] + wsum[2] + wsum[3];
    ap[b * 512 + t] = e0 / s;
    ap[b * 512 + t + 256] = e1 / s;
}

// cp[b,:128]=sum_s ac*hd2 ; cp[b,128:]=sum_l ap*t2
__global__ void k_cp(const float* __restrict__ ac, const float* __restrict__ ap,
                     const float* __restrict__ hd2, const bf16* __restrict__ t2,
                     float* __restrict__ cp) {
    int b = blockIdx.x, m = threadIdx.x;  // 128 threads
    float c = 0.f;
    for (int s = 0; s < 45; s++) c += ac[b * 45 + s] * hd2[(b * 45 + s) * 128 + m];
    float p = 0.f;
    for (int l = 0; l < 512; l++) p += ap[b * 512 + l] * tofl(t2[((long)b * 512 + l) * 128 + m]);
    cp[b * 256 + m] = c;
    cp[b * 256 + 128 + m] = p;
}

__global__ void k_out(const float* __restrict__ c2o, const float* __restrict__ outW,
                      const float* __restrict__ outb, float* __restrict__ out) {
    int b = blockIdx.x, t = threadIdx.x;  // 64 threads
    float a = 0.f;
    for (int j = t; j < 512; j += 64) a += c2o[b * 512 + j] * outW[j];
    for (int off = 32; off; off >>= 1) a += __shfl_xor(a, off);
    if (t == 0) out[b] = a + outb[0];
}

extern "C" void kernel_launch(void* const* d_in, const int* in_sizes, int n_in,
                              void* d_out, int out_size, void* d_ws, size_t ws_size,
                              hipStream_t stream) {
    const float* x        = (const float*)d_in[0];
    const int*   ei       = (const int*)d_in[1];
    const int*   tgt      = (const int*)d_in[2];
    const float* proteins = (const float*)d_in[4];
    const float* gW1 = (const float*)d_in[5];  const float* gb1 = (const float*)d_in[6];
    const float* gW2 = (const float*)d_in[7];  const float* gb2 = (const float*)d_in[8];
    const float* gW3 = (const float*)d_in[9];  const float* gb3 = (const float*)d_in[10];
    const float* fc1_W = (const float*)d_in[11]; const float* fc1_b = (const float*)d_in[12];
    const float* fc2_W = (const float*)d_in[13]; const float* fc2_b = (const float*)d_in[14];
    const float* bert1_W = (const float*)d_in[15]; const float* bert1_b = (const float*)d_in[16];
    const float* bert2_W = (const float*)d_in[17]; const float* bert2_b = (const float*)d_in[18];
    const float* W_b = (const float*)d_in[19];
    const float* W_c = (const float*)d_in[20];
    const float* W_p = (const float*)d_in[21];
    const float* w_hc = (const float*)d_in[22];
    const float* w_hp = (const float*)d_in[23];
    const float* cat1_W = (const float*)d_in[24]; const float* cat1_b = (const float*)d_in[25];
    const float* cat2_W = (const float*)d_in[26]; const float* cat2_b = (const float*)d_in[27];
    const float* out_W = (const float*)d_in[28]; const float* out_b = (const float*)d_in[29];

    const int* src = ei;            // edge_index[0]
    const int* dst = ei + NE;       // edge_index[1]

    // ---- workspace layout (bump allocator, 256B aligned; total ~62 MiB) ----
    char* w = (char*)d_ws;
    auto alloc = [&](size_t bytes) -> void* {
        void* p = (void*)w;
        w += (bytes + 255) & ~(size_t)255;
        return p;
    };
    int*   cnt       = (int*)alloc(NNODE * 4);
    int*   row_start = (int*)alloc((NNODE + 1) * 4);
    int*   cursor    = (int*)alloc(NNODE * 4);
    int*   colv      = (int*)alloc(NE * 4);
    float* valv      = (float*)alloc(NE * 4);
    float* dinv      = (float*)alloc(NNODE * 4);
    float* deginv    = (float*)alloc(NNODE * 4);
    float* h_a       = (float*)alloc((size_t)NNODE * 256 * 4);  // 5.24MB (also Wpt alias start)
    float* h_b       = (float*)alloc((size_t)NNODE * 128 * 4);  // 2.62MB
    float* hd        = (float*)alloc((size_t)5760 * 256 * 4);   // 5.90MB (dense, zero-padded)
    bf16*  fc1o      = (bf16*)alloc((size_t)5760 * 1024 * 2);   // 11.80MB (aliased later by Cb)
    float* hd2       = (float*)alloc((size_t)5760 * 128 * 4);   // 2.95MB
    bf16*  t1        = (bf16*)alloc((size_t)65536 * 128 * 2);   // 16.78MB (aliased later by tWb)
    bf16*  t2        = (bf16*)alloc((size_t)65536 * 128 * 2);   // 16.78MB
    float* Wcx       = (float*)alloc((size_t)NB * 32 * 45 * 4);
    float* Hc        = (float*)alloc((size_t)NB * 32 * 45 * 4);
    float* ac        = (float*)alloc((size_t)NB * 45 * 4);
    float* ap        = (float*)alloc((size_t)NB * 512 * 4);
    float* cp        = (float*)alloc((size_t)NB * 256 * 4);
    float* c1o       = (float*)alloc((size_t)NB * 1024 * 4);
    float* c2o       = (float*)alloc((size_t)NB * 512 * 4);
    // aliases (lifetimes disjoint):
    bf16*  tWb = t1;                     // t1 dead after bert2
    float* Cb  = (float*)fc1o;           // fc1o dead after fc2; 11,796,480 B == fc1o bytes
    float* Wpt = h_a;                    // 8.39MB spans h_a+h_b+0.53MB of hd; all dead by k_wpt

    // ---- graph preprocessing ----
    hipMemsetAsync(cnt, 0, NNODE * 4, stream);
    hipMemsetAsync(cursor, 0, NNODE * 4, stream);
    hipMemsetAsync(hd, 0, (size_t)5760 * 256 * 4, stream);
    k_count<<<(NE + 255) / 256, 256, 0, stream>>>(dst, cnt, NE);
    k_scan<<<1, 1024, 0, stream>>>(cnt, row_start, dinv, deginv, NNODE);
    k_fill<<<(NE + 255) / 256, 256, 0, stream>>>(src, dst, row_start, cursor, colv, valv, dinv, NE);

    // ---- GCN stack ----
    gemm_k<float, float, 0, false><<<dim3(NNODE / 64, 2), 256, 0, stream>>>(x, gW1, nullptr, h_a, NNODE, 128, 78, nullptr);
    k_agg<false><<<(NNODE * 128 + 255) / 256, 256, 0, stream>>>(h_a, deginv, row_start, colv, valv, gb1, h_b, 128);
    gemm_k<float, float, 0, false><<<dim3(NNODE / 64, 2), 256, 0, stream>>>(h_b, gW2, nullptr, h_a, NNODE, 128, 128, nullptr);
    k_agg<false><<<(NNODE * 128 + 255) / 256, 256, 0, stream>>>(h_a, deginv, row_start, colv, valv, gb2, h_b, 128);
    gemm_k<float, float, 0, false><<<dim3(NNODE / 64, 4), 256, 0, stream>>>(h_b, gW3, nullptr, h_a, NNODE, 256, 128, nullptr);
    k_agg<true><<<(NNODE * 256 + 255) / 256, 256, 0, stream>>>(h_a, deginv, row_start, colv, valv, gb3, hd, 256);

    // ---- dense graph MLP ----
    gemm_k<float, bf16, 1, false><<<dim3(90, 16), 256, 0, stream>>>(hd, fc1_W, fc1_b, fc1o, 5760, 1024, 256, nullptr);
    gemm_k<bf16, float, 1, false><<<dim3(90, 2), 256, 0, stream>>>(fc1o, fc2_W, fc2_b, hd2, 5760, 128, 1024, nullptr);

    // ---- protein branch (gather fused into bert1 A-load) ----
    gemm_k<float, bf16, 1, true><<<dim3(1024, 2), 256, 0, stream>>>(proteins, bert1_W, bert1_b, t1, 65536, 128, 1280, tgt);
    gemm_k<bf16, bf16, 1, false><<<dim3(1024, 2), 256, 0, stream>>>(t1, bert2_W, bert2_b, t2, 65536, 128, 128, nullptr);
    gemm_k<bf16, bf16, 0, false><<<dim3(1024, 2), 256, 0, stream>>>(t2, W_b, nullptr, tWb, 65536, 128, 128, nullptr);

    // ---- co-attention ----
    k_C<<<dim3(NB, 8), 256, 0, stream>>>(tWb, hd2, Cb);
    k_wcx<<<NB, 256, 0, stream>>>(W_c, hd2, Wcx);
    k_wpt<<<dim3(NB, 8), 256, 0, stream>>>(W_p, t2, Wpt);
    k_hc<<<NB, 256, 0, stream>>>(Wpt, Cb, Wcx, Hc);
    k_hp<<<NB, 256, 0, stream>>>(Wcx, Cb, Wpt);     // Hp in-place
    k_ac<<<NB, 64, 0, stream>>>(w_hc, Hc, ac);
    k_ap<<<NB, 256, 0, stream>>>(w_hp, Wpt, ap);
    k_cp<<<NB, 128, 0, stream>>>(ac, ap, hd2, t2, cp);

    // ---- head MLP ----
    gemm_k<float, float, 1, false><<<dim3(2, 16), 256, 0, stream>>>(cp, cat1_W, cat1_b, c1o, 128, 1024, 256, nullptr);
    gemm_k<float, float, 1, false><<<dim3(2, 8), 256, 0, stream>>>(c1o, cat2_W, cat2_b, c2o, 128, 512, 1024, nullptr);
    k_out<<<NB, 64, 0, stream>>>(c2o, out_W, out_b, (float*)d_out);
}